// Round 17
// baseline (126.810 us; speedup 1.0000x reference)
//
#include <hip/hip_runtime.h>
#include <hip/hip_fp16.h>

#define PTAB_STRIDE 64   // halves per row = 128 B

typedef float    f32x4 __attribute__((ext_vector_type(4)));
typedef _Float16 half8 __attribute__((ext_vector_type(8)));
typedef _Float16 h2    __attribute__((ext_vector_type(2)));

__device__ __forceinline__ h2 u2h2(unsigned int u) {
    union { unsigned int u; h2 h; } c; c.u = u; return c.h;
}

__device__ __forceinline__ float fdot2x(h2 a, h2 b, float c) {
#if __has_builtin(__builtin_amdgcn_fdot2)
    return __builtin_amdgcn_fdot2(a, b, c, false);
#else
    return c + (float)a[0] * (float)b[0] + (float)a[1] * (float)b[1];
#endif
}

__device__ __forceinline__ float clamp9(float a) {
#if __has_builtin(__builtin_amdgcn_fmed3f)
    return __builtin_amdgcn_fmed3f(a, -9.f, 9.f);
#else
    return fminf(9.f, fmaxf(-9.f, a));
#endif
}

// ---------------------------------------------------------------------------
// Kernel 0: pack B-fragments (W^T, fp16, zero-padded to K=320 x N=64) in the
// exact mfma_f32_16x16x32_f16 per-lane layout, + fused bias table.
// ---------------------------------------------------------------------------
__global__ __launch_bounds__(64) void prep_kernel(
    const float* __restrict__ Wih, const float* __restrict__ bih,
    const float* __restrict__ bhh, __half* __restrict__ Bfrag,
    float* __restrict__ bias64)
{
    const int lane = threadIdx.x;
    const int st   = blockIdx.x;
    if (st == 40) {
        if (lane < 64) bias64[lane] = (lane < 50) ? bih[lane] + bhh[lane] : 0.f;
        return;
    }
    const int s  = st >> 2, t = st & 3;
    const int n  = 16 * t + (lane & 15);
    const int kb = lane >> 4;
    half8 v;
    #pragma unroll
    for (int j = 0; j < 8; ++j) {
        const int k = 32 * s + 8 * kb + j;
        float w = 0.f;
        if (n < 50 && k < 300) w = Wih[n * 300 + k];
        v[j] = (_Float16)w;
    }
    *reinterpret_cast<half8*>(Bfrag + ((size_t)st * 64 + lane) * 8) = v;
}

// ---------------------------------------------------------------------------
// Phase 1: ptab[v][h] = fp16( dot(emb[v,:], W_ih[h,:]) + b_ih + b_hh )
// One wave per 16 vocab rows, 4 N-tile accumulators, 40 MFMAs. (proven r8)
// ---------------------------------------------------------------------------
__global__ __launch_bounds__(64) void ptab_mfma(
    const float* __restrict__ emb, const __half* __restrict__ Bfrag,
    const float* __restrict__ bias64, __half* __restrict__ ptab)
{
    const int lane = threadIdx.x;
    const int v0   = blockIdx.x * 16;
    const int m    = lane & 15;
    const int kb   = lane >> 4;
    const float* Erow = emb + (size_t)(v0 + m) * 300;
    const half8* BF   = reinterpret_cast<const half8*>(Bfrag);

    f32x4 acc[4];
    #pragma unroll
    for (int t = 0; t < 4; ++t) acc[t] = (f32x4){0.f, 0.f, 0.f, 0.f};

    #pragma unroll
    for (int s = 0; s < 9; ++s) {
        const int k0 = 32 * s + 8 * kb;
        float4 p0 = *(const float4*)(Erow + k0);
        float4 p1 = *(const float4*)(Erow + k0 + 4);
        half8 a;
        a[0] = (_Float16)p0.x; a[1] = (_Float16)p0.y;
        a[2] = (_Float16)p0.z; a[3] = (_Float16)p0.w;
        a[4] = (_Float16)p1.x; a[5] = (_Float16)p1.y;
        a[6] = (_Float16)p1.z; a[7] = (_Float16)p1.w;
        #pragma unroll
        for (int t = 0; t < 4; ++t)
            acc[t] = __builtin_amdgcn_mfma_f32_16x16x32_f16(
                a, BF[(4 * s + t) * 64 + lane], acc[t], 0, 0, 0);
    }
    {   // tail K-step s=9: k = 288..319, valid only k < 300
        half8 a;
        #pragma unroll
        for (int j = 0; j < 8; ++j) {
            const int k = 288 + 8 * kb + j;
            float e = 0.f;
            if (k < 300) e = Erow[k];
            a[j] = (_Float16)e;
        }
        #pragma unroll
        for (int t = 0; t < 4; ++t)
            acc[t] = __builtin_amdgcn_mfma_f32_16x16x32_f16(
                a, BF[(36 + t) * 64 + lane], acc[t], 0, 0, 0);
    }

    const int nn = lane & 15;
    #pragma unroll
    for (int t = 0; t < 4; ++t) {
        const float bt = bias64[16 * t + nn];
        #pragma unroll
        for (int r = 0; r < 4; ++r)
            ptab[(size_t)(v0 + 4 * kb + r) * PTAB_STRIDE + 16 * t + nn] =
                (__half)(acc[t][r] + bt);
    }
}

// ---------------------------------------------------------------------------
// Phase 2: recurrence + head. One sequence per wave, 256 waves (1/CU).
// r16 skeleton, with W_hh pinned in AGPRs a0..a24 via explicit
// v_accvgpr_write/read inline asm (unified VGPR/AGPR file on gfx950; no
// MFMA in this kernel so a0..a24 are free). This bypasses the register
// allocator entirely: W can no longer spill to scratch, and its per-use
// cost is a ~2-4 cyc VALU read issued during the DS broadcast wait.
// Decisive test between "W-in-scratch caused the ~96 cyc/step residual"
// (expect −15-20 us) and "spills were AGPR-backed already" (expect null).
// ---------------------------------------------------------------------------
__global__ __launch_bounds__(64, 1) void rnn_kernel(
    const int* __restrict__ tokens, const __half* __restrict__ ptab,
    const float* __restrict__ Whh,
    const float* __restrict__ Wfc, const float* __restrict__ bfc,
    float* __restrict__ out)
{
    __shared__ int stok[544];
    __shared__ __align__(16) _Float16 hbuf[64];
    const int lane = threadIdx.x;
    const int b    = blockIdx.x;
    const int hc   = lane < 50 ? lane : 49;

    #pragma unroll
    for (int k = 0; k < 8; ++k)
        stok[lane + 64 * k] = tokens[b * 512 + lane + 64 * k];
    if (lane < 32) stok[512 + lane] = 0;     // pad: token 0 -> valid row
    __syncthreads();

    // W_hh row for this lane: 25 packed fp16 pairs -> AGPRs a0..a24.
    {
        unsigned int wtmp;
#define WSTORE(J)                                                            \
        {                                                                    \
            float2 w2 = *(const float2*)(Whh + hc * 50 + 2 * (J));           \
            union { h2 h; unsigned int u; } c;                               \
            c.h = (h2){(_Float16)w2.x, (_Float16)w2.y};                      \
            wtmp = c.u;                                                      \
            asm volatile("v_accvgpr_write_b32 a" #J ", %0"                   \
                         :: "v"(wtmp) : "a" #J);                             \
        }
        WSTORE(0)  WSTORE(1)  WSTORE(2)  WSTORE(3)  WSTORE(4)
        WSTORE(5)  WSTORE(6)  WSTORE(7)  WSTORE(8)  WSTORE(9)
        WSTORE(10) WSTORE(11) WSTORE(12) WSTORE(13) WSTORE(14)
        WSTORE(15) WSTORE(16) WSTORE(17) WSTORE(18) WSTORE(19)
        WSTORE(20) WSTORE(21) WSTORE(22) WSTORE(23) WSTORE(24)
#undef WSTORE
    }

#define WR(J)                                                                \
    ({ unsigned int _w;                                                      \
       asm volatile("v_accvgpr_read_b32 %0, a" #J : "=v"(_w));               \
       u2h2(_w); })

    float h = 0.f;

#define GA(T) ptab[(size_t)(T) * PTAB_STRIDE + lane]

    __half x0 = GA(stok[0]), x1 = GA(stok[1]), x2 = GA(stok[2]), x3 = GA(stok[3]);
    __half x4 = GA(stok[4]), x5 = GA(stok[5]), x6 = GA(stok[6]), x7 = GA(stok[7]);

#define SL(Q, i) __builtin_shufflevector(Q, Q, 2*(i), 2*(i)+1)

#define RNN_STEP(XV)                                                         \
    {                                                                        \
        hbuf[lane] = (_Float16)h;          /* ds_write_b16, in-order */      \
        const half8* H8 = (const half8*)hbuf;                                \
        half8 q0 = H8[0], q1 = H8[1];                                        \
        float s0 = 0.f, s1 = 0.f, s2 = 0.f, s3 = 0.f;                        \
        s0 = fdot2x(SL(q0,0), WR(0),  s0); s1 = fdot2x(SL(q0,1), WR(1),  s1);\
        s2 = fdot2x(SL(q0,2), WR(2),  s2); s3 = fdot2x(SL(q0,3), WR(3),  s3);\
        s0 = fdot2x(SL(q1,0), WR(4),  s0); s1 = fdot2x(SL(q1,1), WR(5),  s1);\
        s2 = fdot2x(SL(q1,2), WR(6),  s2); s3 = fdot2x(SL(q1,3), WR(7),  s3);\
        half8 q2 = H8[2], q3 = H8[3];                                        \
        s0 = fdot2x(SL(q2,0), WR(8),  s0); s1 = fdot2x(SL(q2,1), WR(9),  s1);\
        s2 = fdot2x(SL(q2,2), WR(10), s2); s3 = fdot2x(SL(q2,3), WR(11), s3);\
        s0 = fdot2x(SL(q3,0), WR(12), s0); s1 = fdot2x(SL(q3,1), WR(13), s1);\
        s2 = fdot2x(SL(q3,2), WR(14), s2); s3 = fdot2x(SL(q3,3), WR(15), s3);\
        half8 q4 = H8[4], q5 = H8[5];                                        \
        h2 q6 = *(const h2*)(hbuf + 48);                                     \
        s0 = fdot2x(SL(q4,0), WR(16), s0); s1 = fdot2x(SL(q4,1), WR(17), s1);\
        s2 = fdot2x(SL(q4,2), WR(18), s2); s3 = fdot2x(SL(q4,3), WR(19), s3);\
        s0 = fdot2x(SL(q5,0), WR(20), s0); s1 = fdot2x(SL(q5,1), WR(21), s1);\
        s2 = fdot2x(SL(q5,2), WR(22), s2); s3 = fdot2x(SL(q5,3), WR(23), s3);\
        s0 = fdot2x(q6,       WR(24), s0);                                   \
        float a = ((float)(XV) + (s1 + s3)) + (s0 + s2);                     \
        a = clamp9(a);                                                       \
        float e = __expf(2.f * a);                                           \
        h = fmaf(-2.f, __builtin_amdgcn_rcpf(e + 1.f), 1.f);                 \
    }

    for (int t = 0; t < 512; t += 8) {
        // token indices read as transients; gathers issued 8 steps ahead
        __half n0 = GA(stok[t + 8]);
        __half n1 = GA(stok[t + 9]);
        __half n2 = GA(stok[t + 10]);
        __half n3 = GA(stok[t + 11]);
        __half n4 = GA(stok[t + 12]);
        __half n5 = GA(stok[t + 13]);
        __half n6 = GA(stok[t + 14]);
        __half n7 = GA(stok[t + 15]);

        RNN_STEP(x0); RNN_STEP(x1); RNN_STEP(x2); RNN_STEP(x3);
        RNN_STEP(x4); RNN_STEP(x5); RNN_STEP(x6); RNN_STEP(x7);

        x0 = n0; x1 = n1; x2 = n2; x3 = n3;
        x4 = n4; x5 = n5; x6 = n6; x7 = n7;
    }
#undef RNN_STEP
#undef SL
#undef WR
#undef GA

    // ---- head: out[b][o] = sum_h h[h] * W_fc[o][h] + b_fc[o] ----
    float hv = (lane < 50) ? h : 0.f;
    #pragma unroll
    for (int o = 0; o < 4; ++o) {
        float w = (lane < 50) ? Wfc[o * 50 + lane] : 0.f;
        float p = hv * w;
        #pragma unroll
        for (int s = 32; s > 0; s >>= 1) p += __shfl_xor(p, s, 64);
        if (lane == 0) out[b * 4 + o] = p + bfc[o];
    }
}

extern "C" void kernel_launch(void* const* d_in, const int* in_sizes, int n_in,
                              void* d_out, int out_size, void* d_ws, size_t ws_size,
                              hipStream_t stream)
{
    const int*   tokens = (const int*)d_in[0];
    const float* emb    = (const float*)d_in[1];
    const float* Wih    = (const float*)d_in[2];
    const float* Whh    = (const float*)d_in[3];
    const float* bih    = (const float*)d_in[4];
    const float* bhh    = (const float*)d_in[5];
    const float* Wfc    = (const float*)d_in[6];
    const float* bfc    = (const float*)d_in[7];

    char* ws = (char*)d_ws;
    __half* ptab   = (__half*)ws;                       // 6,400,000 B
    __half* Bfrag  = (__half*)(ws + 6400000);           //    40,960 B
    float*  bias64 = (float*)(ws + 6440960);            //       256 B
    float*  outp   = (float*)d_out;

    prep_kernel<<<41, 64, 0, stream>>>(Wih, bih, bhh, Bfrag, bias64);
    ptab_mfma<<<3125, 64, 0, stream>>>(emb, Bfrag, bias64, ptab);
    rnn_kernel<<<256, 64, 0, stream>>>(tokens, ptab, Whh, Wfc, bfc, outp);
}

// Round 18
// 109.770 us; speedup vs baseline: 1.1552x; 1.1552x over previous
//
#include <hip/hip_runtime.h>
#include <hip/hip_fp16.h>

#define PTAB_STRIDE 64   // halves per row = 128 B

typedef float    f32x4 __attribute__((ext_vector_type(4)));
typedef _Float16 half8 __attribute__((ext_vector_type(8)));
typedef _Float16 h2    __attribute__((ext_vector_type(2)));

__device__ __forceinline__ h2 u2h2(unsigned int u) {
    union { unsigned int u; h2 h; } c; c.u = u; return c.h;
}

__device__ __forceinline__ float fdot2x(h2 a, h2 b, float c) {
#if __has_builtin(__builtin_amdgcn_fdot2)
    return __builtin_amdgcn_fdot2(a, b, c, false);
#else
    return c + (float)a[0] * (float)b[0] + (float)a[1] * (float)b[1];
#endif
}

__device__ __forceinline__ float clamp9(float a) {
#if __has_builtin(__builtin_amdgcn_fmed3f)
    return __builtin_amdgcn_fmed3f(a, -9.f, 9.f);
#else
    return fminf(9.f, fmaxf(-9.f, a));
#endif
}

// DPP quad-perm xor1 (VALU pipe): lane l gets lane l^1's value.
#define DPPX1(v) \
    ((unsigned)__builtin_amdgcn_update_dpp(0, (int)(v), 0xB1, 0xf, 0xf, true))

// ---------------------------------------------------------------------------
// Kernel 0: pack B-fragments (W^T, fp16, zero-padded to K=320 x N=64) in the
// exact mfma_f32_16x16x32_f16 per-lane layout, + fused bias table.
// ---------------------------------------------------------------------------
__global__ __launch_bounds__(64) void prep_kernel(
    const float* __restrict__ Wih, const float* __restrict__ bih,
    const float* __restrict__ bhh, __half* __restrict__ Bfrag,
    float* __restrict__ bias64)
{
    const int lane = threadIdx.x;
    const int st   = blockIdx.x;
    if (st == 40) {
        if (lane < 64) bias64[lane] = (lane < 50) ? bih[lane] + bhh[lane] : 0.f;
        return;
    }
    const int s  = st >> 2, t = st & 3;
    const int n  = 16 * t + (lane & 15);
    const int kb = lane >> 4;
    half8 v;
    #pragma unroll
    for (int j = 0; j < 8; ++j) {
        const int k = 32 * s + 8 * kb + j;
        float w = 0.f;
        if (n < 50 && k < 300) w = Wih[n * 300 + k];
        v[j] = (_Float16)w;
    }
    *reinterpret_cast<half8*>(Bfrag + ((size_t)st * 64 + lane) * 8) = v;
}

// ---------------------------------------------------------------------------
// Phase 1: ptab[v][h] = fp16( dot(emb[v,:], W_ih[h,:]) + b_ih + b_hh )
// One wave per 16 vocab rows, 4 N-tile accumulators, 40 MFMAs. (proven r8)
// ---------------------------------------------------------------------------
__global__ __launch_bounds__(64) void ptab_mfma(
    const float* __restrict__ emb, const __half* __restrict__ Bfrag,
    const float* __restrict__ bias64, __half* __restrict__ ptab)
{
    const int lane = threadIdx.x;
    const int v0   = blockIdx.x * 16;
    const int m    = lane & 15;
    const int kb   = lane >> 4;
    const float* Erow = emb + (size_t)(v0 + m) * 300;
    const half8* BF   = reinterpret_cast<const half8*>(Bfrag);

    f32x4 acc[4];
    #pragma unroll
    for (int t = 0; t < 4; ++t) acc[t] = (f32x4){0.f, 0.f, 0.f, 0.f};

    #pragma unroll
    for (int s = 0; s < 9; ++s) {
        const int k0 = 32 * s + 8 * kb;
        float4 p0 = *(const float4*)(Erow + k0);
        float4 p1 = *(const float4*)(Erow + k0 + 4);
        half8 a;
        a[0] = (_Float16)p0.x; a[1] = (_Float16)p0.y;
        a[2] = (_Float16)p0.z; a[3] = (_Float16)p0.w;
        a[4] = (_Float16)p1.x; a[5] = (_Float16)p1.y;
        a[6] = (_Float16)p1.z; a[7] = (_Float16)p1.w;
        #pragma unroll
        for (int t = 0; t < 4; ++t)
            acc[t] = __builtin_amdgcn_mfma_f32_16x16x32_f16(
                a, BF[(4 * s + t) * 64 + lane], acc[t], 0, 0, 0);
    }
    {   // tail K-step s=9: k = 288..319, valid only k < 300
        half8 a;
        #pragma unroll
        for (int j = 0; j < 8; ++j) {
            const int k = 288 + 8 * kb + j;
            float e = 0.f;
            if (k < 300) e = Erow[k];
            a[j] = (_Float16)e;
        }
        #pragma unroll
        for (int t = 0; t < 4; ++t)
            acc[t] = __builtin_amdgcn_mfma_f32_16x16x32_f16(
                a, BF[(36 + t) * 64 + lane], acc[t], 0, 0, 0);
    }

    const int nn = lane & 15;
    #pragma unroll
    for (int t = 0; t < 4; ++t) {
        const float bt = bias64[16 * t + nn];
        #pragma unroll
        for (int r = 0; r < 4; ++r)
            ptab[(size_t)(v0 + 4 * kb + r) * PTAB_STRIDE + 16 * t + nn] =
                (__half)(acc[t][r] + bt);
    }
}

// ---------------------------------------------------------------------------
// Phase 2: recurrence + head. One sequence per wave, 256 waves (1/CU).
// NO LDS IN THE LOOP: h broadcast via batched v_readlane -> SGPRs.
//   1. cvt h to fp16; DPP xor1; pack -> even lane 2j holds (h[2j],h[2j+1])
//   2. 25 v_readlane (lanes 0,2,..,48) -> 25 SGPRs, all independent
//   3. 25 v_dot2_f32_f16 with SGPR source, 4 chains; dot[j] consumes the
//      SGPR written ~25 instructions earlier -> no VALU->SGPR RAW hazard
//      (r2's readlane attempt interleaved them 1:1 -> ~10 cyc hazard each)
// This removes the ~200-cyc DS write->read round trip from the serial chain
// that r9-r16 could never get below (400 cyc/step).
// ---------------------------------------------------------------------------
__global__ __launch_bounds__(64, 1) void rnn_kernel(
    const int* __restrict__ tokens, const __half* __restrict__ ptab,
    const float* __restrict__ Whh,
    const float* __restrict__ Wfc, const float* __restrict__ bfc,
    float* __restrict__ out)
{
    __shared__ int stok[544];
    const int lane = threadIdx.x;
    const int b    = blockIdx.x;
    const int hc   = lane < 50 ? lane : 49;

    #pragma unroll
    for (int k = 0; k < 8; ++k)
        stok[lane + 64 * k] = tokens[b * 512 + lane + 64 * k];
    if (lane < 32) stok[512 + lane] = 0;     // pad: token 0 -> valid row
    __syncthreads();

    // W_hh row for this lane: 25 packed fp16 pairs (demand ~45 VGPR -> fits).
    unsigned int wh_u[25];
    #pragma unroll
    for (int j = 0; j < 25; ++j) {
        float2 w2 = *(const float2*)(Whh + hc * 50 + 2 * j);
        union { h2 h; unsigned int u; } c;
        c.h = (h2){(_Float16)w2.x, (_Float16)w2.y};
        wh_u[j] = c.u;
    }

    float h = 0.f;

#define GA(T) ptab[(size_t)(T) * PTAB_STRIDE + lane]

    __half x0 = GA(stok[0]), x1 = GA(stok[1]), x2 = GA(stok[2]), x3 = GA(stok[3]);
    __half x4 = GA(stok[4]), x5 = GA(stok[5]), x6 = GA(stok[6]), x7 = GA(stok[7]);

#define WH(j) u2h2(wh_u[j])
#define RL(J) ((unsigned)__builtin_amdgcn_readlane((int)pk, 2 * (J)))

#define RNN_STEP(XV)                                                         \
    {                                                                        \
        union { _Float16 hf; unsigned short us; } hcv;                       \
        hcv.hf = (_Float16)h;                                                \
        unsigned hu = (unsigned)hcv.us;                                      \
        unsigned nb = DPPX1(hu);                                             \
        unsigned pk = hu | (nb << 16);   /* even lane 2j: (h[2j],h[2j+1]) */ \
        unsigned g0  = RL(0),  g1  = RL(1),  g2  = RL(2),  g3  = RL(3);      \
        unsigned g4  = RL(4),  g5  = RL(5),  g6  = RL(6),  g7  = RL(7);      \
        unsigned g8  = RL(8),  g9  = RL(9),  g10 = RL(10), g11 = RL(11);     \
        unsigned g12 = RL(12), g13 = RL(13), g14 = RL(14), g15 = RL(15);     \
        unsigned g16 = RL(16), g17 = RL(17), g18 = RL(18), g19 = RL(19);     \
        unsigned g20 = RL(20), g21 = RL(21), g22 = RL(22), g23 = RL(23);     \
        unsigned g24 = RL(24);                                               \
        float s0 = 0.f, s1 = 0.f, s2 = 0.f, s3 = 0.f;                        \
        s0 = fdot2x(u2h2(g0),  WH(0),  s0); s1 = fdot2x(u2h2(g1),  WH(1),  s1);\
        s2 = fdot2x(u2h2(g2),  WH(2),  s2); s3 = fdot2x(u2h2(g3),  WH(3),  s3);\
        s0 = fdot2x(u2h2(g4),  WH(4),  s0); s1 = fdot2x(u2h2(g5),  WH(5),  s1);\
        s2 = fdot2x(u2h2(g6),  WH(6),  s2); s3 = fdot2x(u2h2(g7),  WH(7),  s3);\
        s0 = fdot2x(u2h2(g8),  WH(8),  s0); s1 = fdot2x(u2h2(g9),  WH(9),  s1);\
        s2 = fdot2x(u2h2(g10), WH(10), s2); s3 = fdot2x(u2h2(g11), WH(11), s3);\
        s0 = fdot2x(u2h2(g12), WH(12), s0); s1 = fdot2x(u2h2(g13), WH(13), s1);\
        s2 = fdot2x(u2h2(g14), WH(14), s2); s3 = fdot2x(u2h2(g15), WH(15), s3);\
        s0 = fdot2x(u2h2(g16), WH(16), s0); s1 = fdot2x(u2h2(g17), WH(17), s1);\
        s2 = fdot2x(u2h2(g18), WH(18), s2); s3 = fdot2x(u2h2(g19), WH(19), s3);\
        s0 = fdot2x(u2h2(g20), WH(20), s0); s1 = fdot2x(u2h2(g21), WH(21), s1);\
        s2 = fdot2x(u2h2(g22), WH(22), s2); s3 = fdot2x(u2h2(g23), WH(23), s3);\
        s0 = fdot2x(u2h2(g24), WH(24), s0);                                  \
        float a = ((float)(XV) + (s1 + s3)) + (s0 + s2);                     \
        a = clamp9(a);                                                       \
        float e = __expf(2.f * a);                                           \
        h = fmaf(-2.f, __builtin_amdgcn_rcpf(e + 1.f), 1.f);                 \
    }

    for (int t = 0; t < 512; t += 8) {
        // token indices read as transients; gathers issued 8 steps ahead
        __half n0 = GA(stok[t + 8]);
        __half n1 = GA(stok[t + 9]);
        __half n2 = GA(stok[t + 10]);
        __half n3 = GA(stok[t + 11]);
        __half n4 = GA(stok[t + 12]);
        __half n5 = GA(stok[t + 13]);
        __half n6 = GA(stok[t + 14]);
        __half n7 = GA(stok[t + 15]);

        RNN_STEP(x0); RNN_STEP(x1); RNN_STEP(x2); RNN_STEP(x3);
        RNN_STEP(x4); RNN_STEP(x5); RNN_STEP(x6); RNN_STEP(x7);

        x0 = n0; x1 = n1; x2 = n2; x3 = n3;
        x4 = n4; x5 = n5; x6 = n6; x7 = n7;
    }
#undef RNN_STEP
#undef RL
#undef WH
#undef GA

    // ---- head: out[b][o] = sum_h h[h] * W_fc[o][h] + b_fc[o] ----
    float hv = (lane < 50) ? h : 0.f;
    #pragma unroll
    for (int o = 0; o < 4; ++o) {
        float w = (lane < 50) ? Wfc[o * 50 + lane] : 0.f;
        float p = hv * w;
        #pragma unroll
        for (int s = 32; s > 0; s >>= 1) p += __shfl_xor(p, s, 64);
        if (lane == 0) out[b * 4 + o] = p + bfc[o];
    }
}

extern "C" void kernel_launch(void* const* d_in, const int* in_sizes, int n_in,
                              void* d_out, int out_size, void* d_ws, size_t ws_size,
                              hipStream_t stream)
{
    const int*   tokens = (const int*)d_in[0];
    const float* emb    = (const float*)d_in[1];
    const float* Wih    = (const float*)d_in[2];
    const float* Whh    = (const float*)d_in[3];
    const float* bih    = (const float*)d_in[4];
    const float* bhh    = (const float*)d_in[5];
    const float* Wfc    = (const float*)d_in[6];
    const float* bfc    = (const float*)d_in[7];

    char* ws = (char*)d_ws;
    __half* ptab   = (__half*)ws;                       // 6,400,000 B
    __half* Bfrag  = (__half*)(ws + 6400000);           //    40,960 B
    float*  bias64 = (float*)(ws + 6440960);            //       256 B
    float*  outp   = (float*)d_out;

    prep_kernel<<<41, 64, 0, stream>>>(Wih, bih, bhh, Bfrag, bias64);
    ptab_mfma<<<3125, 64, 0, stream>>>(emb, Bfrag, bias64, ptab);
    rnn_kernel<<<256, 64, 0, stream>>>(tokens, ptab, Whh, Wfc, bfc, outp);
}